// Round 1
// baseline (17351.689 us; speedup 1.0000x reference)
//
#include <hip/hip_runtime.h>
#include <hip/hip_bf16.h>

#define V_SZ 50257
#define L_N 12
#define D_MODEL 768
#define S_LEN 1024
#define FF_DIM 3072
#define NTOK 2048  // B*S

// ---------------- embedding: x = tok_emb[ids] + pos_emb ----------------
__global__ __launch_bounds__(256) void embed_kernel(
    const int* __restrict__ ids, const float* __restrict__ tok,
    const float* __restrict__ pos, float* __restrict__ x) {
  int idx = blockIdx.x * 256 + threadIdx.x;  // over NTOK*D
  if (idx >= NTOK * D_MODEL) return;
  int d = idx % D_MODEL;
  int t = (idx / D_MODEL) % S_LEN;
  int id = ids[idx / D_MODEL];
  x[idx] = tok[(size_t)id * D_MODEL + d] + pos[t * D_MODEL + d];
}

// ---------------- LayerNorm: one block (256 thr) per row of 768 ----------------
__global__ __launch_bounds__(256) void ln_kernel(
    const float* __restrict__ in, float* __restrict__ out,
    const float* __restrict__ w, const float* __restrict__ b) {
  int row = blockIdx.x;
  const float* xr = in + (size_t)row * D_MODEL;
  int tid = threadIdx.x;
  float v[3];
  float s = 0.f, ss = 0.f;
#pragma unroll
  for (int i = 0; i < 3; ++i) {
    v[i] = xr[tid + i * 256];
    s += v[i];
    ss += v[i] * v[i];
  }
#pragma unroll
  for (int off = 32; off >= 1; off >>= 1) {
    s += __shfl_xor(s, off, 64);
    ss += __shfl_xor(ss, off, 64);
  }
  __shared__ float smem[8];
  int wave = tid >> 6, lane = tid & 63;
  if (lane == 0) { smem[wave] = s; smem[4 + wave] = ss; }
  __syncthreads();
  s = smem[0] + smem[1] + smem[2] + smem[3];
  ss = smem[4] + smem[5] + smem[6] + smem[7];
  float mean = s * (1.f / D_MODEL);
  float var = ss * (1.f / D_MODEL) - mean * mean;
  float rstd = rsqrtf(var + 1e-5f);
  float* orow = out + (size_t)row * D_MODEL;
#pragma unroll
  for (int i = 0; i < 3; ++i) {
    int d = tid + i * 256;
    orow[d] = (v[i] - mean) * rstd * w[d] + b[d];
  }
}

// ---------------- GEMM C[M][N] = A[M][K] @ B[K][N] (+epilogue) ----------------
// EPI: 0 = +bias, 1 = +bias+gelu(exact), 2 = +bias+residual, 3 = none
// 64x64 tile, BK=16, 256 threads, 4x4 microtile. M multiple of 64, N mult of 64,
// K mult of 16 (all true for the in-model GEMMs).
template <int EPI>
__global__ __launch_bounds__(256) void gemm_nn(
    const float* __restrict__ A, const float* __restrict__ B,
    const float* __restrict__ bias, const float* __restrict__ res,
    float* __restrict__ C, int N, int K) {
  __shared__ float As[16][68];  // As[k][m], pad 68: conflict-free + 16B aligned
  __shared__ float Bs[16][68];  // Bs[k][n]
  int tid = threadIdx.x;
  int bm = blockIdx.y * 64, bn = blockIdx.x * 64;
  int tm = (tid >> 4) << 2, tn = (tid & 15) << 2;
  int ar = tid >> 4, ak = tid & 15;   // A stage: row ar(+16j), col ak
  int br = tid >> 6, bn2 = tid & 63;  // B stage: row br(+4j), col bn2
  float acc[4][4] = {};
  for (int k0 = 0; k0 < K; k0 += 16) {
#pragma unroll
    for (int j = 0; j < 4; ++j)
      As[ak][ar + j * 16] = A[(size_t)(bm + ar + j * 16) * K + k0 + ak];
#pragma unroll
    for (int j = 0; j < 4; ++j)
      Bs[br + j * 4][bn2] = B[(size_t)(k0 + br + j * 4) * N + bn + bn2];
    __syncthreads();
#pragma unroll
    for (int kk = 0; kk < 16; ++kk) {
      const float4 av = *(const float4*)&As[kk][tm];
      const float4 bv = *(const float4*)&Bs[kk][tn];
      const float aa[4] = {av.x, av.y, av.z, av.w};
      const float bb[4] = {bv.x, bv.y, bv.z, bv.w};
#pragma unroll
      for (int i = 0; i < 4; ++i)
#pragma unroll
        for (int j = 0; j < 4; ++j) acc[i][j] = fmaf(aa[i], bb[j], acc[i][j]);
    }
    __syncthreads();
  }
#pragma unroll
  for (int i = 0; i < 4; ++i) {
    size_t base = (size_t)(bm + tm + i) * N + bn + tn;
    float o[4];
#pragma unroll
    for (int j = 0; j < 4; ++j) {
      float v0 = acc[i][j];
      if (EPI != 3) v0 += bias[bn + tn + j];
      if (EPI == 1) v0 = 0.5f * v0 * (1.f + erff(v0 * 0.70710678118654752f));
      if (EPI == 2) v0 += res[base + j];
      o[j] = v0;
    }
    *(float4*)&C[base] = make_float4(o[0], o[1], o[2], o[3]);
  }
}

// ---------------- GEMM-NT for lm_head: C = A[M][K] @ Bt[N][K]^T, ragged N ----------------
__global__ __launch_bounds__(256) void gemm_nt(
    const float* __restrict__ A, const float* __restrict__ Bt,
    float* __restrict__ C, int N, int K) {
  __shared__ float As[16][68];
  __shared__ float Bs[16][68];
  int tid = threadIdx.x;
  int bm = blockIdx.y * 64, bn = blockIdx.x * 64;
  int tm = (tid >> 4) << 2, tn = (tid & 15) << 2;
  int ar = tid >> 4, ak = tid & 15;
  int bnr = tid >> 4, bk = tid & 15;  // B stage: col bnr(+16j), k bk
  float acc[4][4] = {};
  for (int k0 = 0; k0 < K; k0 += 16) {
#pragma unroll
    for (int j = 0; j < 4; ++j)
      As[ak][ar + j * 16] = A[(size_t)(bm + ar + j * 16) * K + k0 + ak];
#pragma unroll
    for (int j = 0; j < 4; ++j) {
      int col = bn + bnr + j * 16;
      Bs[bk][bnr + j * 16] =
          (col < N) ? Bt[(size_t)col * K + k0 + bk] : 0.f;
    }
    __syncthreads();
#pragma unroll
    for (int kk = 0; kk < 16; ++kk) {
      const float4 av = *(const float4*)&As[kk][tm];
      const float4 bv = *(const float4*)&Bs[kk][tn];
      const float aa[4] = {av.x, av.y, av.z, av.w};
      const float bb[4] = {bv.x, bv.y, bv.z, bv.w};
#pragma unroll
      for (int i = 0; i < 4; ++i)
#pragma unroll
        for (int j = 0; j < 4; ++j) acc[i][j] = fmaf(aa[i], bb[j], acc[i][j]);
    }
    __syncthreads();
  }
#pragma unroll
  for (int i = 0; i < 4; ++i)
#pragma unroll
    for (int j = 0; j < 4; ++j) {
      int col = bn + tn + j;
      if (col < N) C[(size_t)(bm + tm + i) * N + col] = acc[i][j];
    }
}

// ---------------- fused causal attention ----------------
// grid (T/64, H, B), 256 threads. qkv rows [token][2304] = [q|k|v], head slice 64.
// Each wave owns 16 q-rows; lane owns output dim d; online softmax over 64-k chunks.
__global__ __launch_bounds__(256) void attn_kernel(
    const float* __restrict__ qkv, float* __restrict__ out) {
  __shared__ float Qs[64][65];
  __shared__ float Ks[64][65];
  __shared__ float Vs[64][65];
  int qt = blockIdx.x, head = blockIdx.y, bb = blockIdx.z;
  int tid = threadIdx.x;
  int lane = tid & 63, wave = tid >> 6;
  int r0 = tid >> 6;
  size_t tokbase = (size_t)bb * S_LEN;
  int qoff = head * 64;
  for (int r = r0; r < 64; r += 4)
    Qs[r][lane] = qkv[(tokbase + qt * 64 + r) * 2304 + qoff + lane];
  float acc[16], mrun[16], lrun[16];
#pragma unroll
  for (int i = 0; i < 16; ++i) { acc[i] = 0.f; mrun[i] = -1e30f; lrun[i] = 0.f; }
  int nch = qt + 1;
  for (int c = 0; c < nch; ++c) {
    __syncthreads();
    for (int r = r0; r < 64; r += 4) {
      size_t rowb = (tokbase + c * 64 + r) * 2304 + qoff + lane;
      Ks[r][lane] = qkv[rowb + 768];
      Vs[r][lane] = qkv[rowb + 1536];
    }
    __syncthreads();
    for (int i = 0; i < 16; ++i) {
      int qrow = qt * 64 + wave * 16 + i;
      int krow = c * 64 + lane;
      float s = -1e30f;
      if (krow <= qrow) {
        float t = 0.f;
#pragma unroll
        for (int d = 0; d < 64; ++d)
          t = fmaf(Qs[wave * 16 + i][d], Ks[lane][d], t);
        s = t * 0.125f;
      }
      float cmax = s;
#pragma unroll
      for (int off = 32; off >= 1; off >>= 1)
        cmax = fmaxf(cmax, __shfl_xor(cmax, off, 64));
      float mnew = fmaxf(mrun[i], cmax);
      float p = (krow <= qrow) ? __expf(s - mnew) : 0.f;
      float ps = p;
#pragma unroll
      for (int off = 32; off >= 1; off >>= 1) ps += __shfl_xor(ps, off, 64);
      float corr = __expf(mrun[i] - mnew);
      mrun[i] = mnew;
      lrun[i] = lrun[i] * corr + ps;
      float a = acc[i] * corr;
#pragma unroll
      for (int k = 0; k < 64; ++k) {
        float pk = __shfl(p, k, 64);
        a = fmaf(pk, Vs[k][lane], a);
      }
      acc[i] = a;
    }
  }
#pragma unroll
  for (int i = 0; i < 16; ++i) {
    int qrow = qt * 64 + wave * 16 + i;
    out[(tokbase + qrow) * 768 + qoff + lane] = acc[i] / lrun[i];
  }
}

extern "C" void kernel_launch(void* const* d_in, const int* in_sizes, int n_in,
                              void* d_out, int out_size, void* d_ws,
                              size_t ws_size, hipStream_t stream) {
  const int* ids = (const int*)d_in[0];
  const float* tok = (const float*)d_in[1];
  const float* pos = (const float*)d_in[2];
  const float* ln1w = (const float*)d_in[3];
  const float* ln1b = (const float*)d_in[4];
  const float* qkvw = (const float*)d_in[5];
  const float* qkvb = (const float*)d_in[6];
  const float* outw = (const float*)d_in[7];
  const float* outb = (const float*)d_in[8];
  const float* ln2w = (const float*)d_in[9];
  const float* ln2b = (const float*)d_in[10];
  const float* ff1w = (const float*)d_in[11];
  const float* ff1b = (const float*)d_in[12];
  const float* ff2w = (const float*)d_in[13];
  const float* ff2b = (const float*)d_in[14];
  const float* lnfw = (const float*)d_in[15];
  const float* lnfb = (const float*)d_in[16];

  float* ws = (float*)d_ws;
  float* x = ws;                          // 2048*768
  float* h = x + NTOK * D_MODEL;          // 2048*768
  float* qkv = h + NTOK * D_MODEL;        // 2048*2304
  float* attn = qkv + NTOK * 3 * D_MODEL; // 2048*768
  float* ff = attn + NTOK * D_MODEL;      // 2048*3072

  embed_kernel<<<(NTOK * D_MODEL + 255) / 256, 256, 0, stream>>>(ids, tok, pos, x);

  for (int l = 0; l < L_N; ++l) {
    ln_kernel<<<NTOK, 256, 0, stream>>>(x, h, ln1w + l * D_MODEL, ln1b + l * D_MODEL);
    gemm_nn<0><<<dim3(36, 32), 256, 0, stream>>>(
        h, qkvw + (size_t)l * D_MODEL * 2304, qkvb + l * 2304, nullptr, qkv,
        2304, D_MODEL);
    attn_kernel<<<dim3(16, 12, 2), 256, 0, stream>>>(qkv, attn);
    gemm_nn<2><<<dim3(12, 32), 256, 0, stream>>>(
        attn, outw + (size_t)l * D_MODEL * D_MODEL, outb + l * D_MODEL, x, x,
        D_MODEL, D_MODEL);
    ln_kernel<<<NTOK, 256, 0, stream>>>(x, h, ln2w + l * D_MODEL, ln2b + l * D_MODEL);
    gemm_nn<1><<<dim3(48, 32), 256, 0, stream>>>(
        h, ff1w + (size_t)l * D_MODEL * FF_DIM, ff1b + l * FF_DIM, nullptr, ff,
        FF_DIM, D_MODEL);
    gemm_nn<2><<<dim3(12, 32), 256, 0, stream>>>(
        ff, ff2w + (size_t)l * FF_DIM * D_MODEL, ff2b + l * D_MODEL, x, x,
        D_MODEL, FF_DIM);
  }
  ln_kernel<<<NTOK, 256, 0, stream>>>(x, h, lnfw, lnfb);
  gemm_nt<<<dim3((V_SZ + 63) / 64, 32), 256, 0, stream>>>(h, tok, (float*)d_out,
                                                          V_SZ, D_MODEL);
}